// Round 4
// baseline (397.424 us; speedup 1.0000x reference)
//
#include <hip/hip_runtime.h>

#define BB 32
#define NHH 32
#define NKVV 8
#define HDD 128
#define SWW 4096
#define DD 4096
#define GG 4
#define QKVC 6144
#define NSPLIT 16
#define CHUNK (SWW / NSPLIT)  // 256
#define KSPB 16
#define SCALE 0.08838834764831845f  // 1/sqrt(128)

// ============ split-K skinny GEMM partial: part[ky][32][ncols] ==============
__global__ __launch_bounds__(256) void skinny_gemm_part(
    const float* __restrict__ x, const float* __restrict__ w,
    float* __restrict__ part, int K, int ncols) {
  __shared__ float2 red[4][64][8];
  const int t = threadIdx.x;
  const int ct = t & 63, kg = t >> 6;
  const long c0 = (long)blockIdx.x * 128 + ct * 2;
  const int Kb = K / KSPB;
  const int klen = Kb / 4;
  const int k0 = blockIdx.y * Kb + kg * klen;
  float2 acc[BB];
#pragma unroll
  for (int r = 0; r < BB; ++r) acc[r] = make_float2(0.f, 0.f);

#pragma unroll 2
  for (int k = k0; k < k0 + klen; k += 4) {
    float2 wv0 = *(const float2*)&w[(long)(k + 0) * ncols + c0];
    float2 wv1 = *(const float2*)&w[(long)(k + 1) * ncols + c0];
    float2 wv2 = *(const float2*)&w[(long)(k + 2) * ncols + c0];
    float2 wv3 = *(const float2*)&w[(long)(k + 3) * ncols + c0];
#pragma unroll
    for (int r = 0; r < BB; ++r) {
      float4 xv = *(const float4*)&x[r * K + k];
      acc[r].x = fmaf(xv.x, wv0.x, acc[r].x);
      acc[r].y = fmaf(xv.x, wv0.y, acc[r].y);
      acc[r].x = fmaf(xv.y, wv1.x, acc[r].x);
      acc[r].y = fmaf(xv.y, wv1.y, acc[r].y);
      acc[r].x = fmaf(xv.z, wv2.x, acc[r].x);
      acc[r].y = fmaf(xv.z, wv2.y, acc[r].y);
      acc[r].x = fmaf(xv.w, wv3.x, acc[r].x);
      acc[r].y = fmaf(xv.w, wv3.y, acc[r].y);
    }
  }
  for (int rc = 0; rc < 4; ++rc) {
    if (rc) __syncthreads();
#pragma unroll
    for (int j = 0; j < 8; ++j) red[kg][ct][j] = acc[rc * 8 + j];
    __syncthreads();
    if (kg == 0) {
#pragma unroll
      for (int j = 0; j < 8; ++j) {
        float2 s0 = red[0][ct][j], s1 = red[1][ct][j];
        float2 s2 = red[2][ct][j], s3 = red[3][ct][j];
        float2 sm = make_float2((s0.x + s1.x) + (s2.x + s3.x),
                                (s0.y + s1.y) + (s2.y + s3.y));
        *(float2*)&part[((long)blockIdx.y * BB + rc * 8 + j) * ncols + c0] = sm;
      }
    }
  }
}

// ============ reduce split-K partials =======================================
__global__ __launch_bounds__(256) void reduce_part(
    const float* __restrict__ part, float* __restrict__ out, long n) {
  long i = (long)blockIdx.x * 256 + threadIdx.x;
  if (i >= n) return;
  float s = 0.f;
#pragma unroll
  for (int j = 0; j < KSPB; ++j) s += part[(long)j * n + i];
  out[i] = s;
}

// ============ rotary ========================================================
__global__ __launch_bounds__(128) void rotary_kernel(
    const float* __restrict__ xqkv, const float* __restrict__ rot,
    float* __restrict__ q_rot, float* __restrict__ k_rot) {
  __shared__ float vec[HDD];
  const int blk = blockIdx.x;
  const int j = threadIdx.x;
  const float* src;
  float* dst;
  if (blk < BB * NHH) {
    int b = blk >> 5, h = blk & 31;
    src = xqkv + (long)b * QKVC + h * HDD;
    dst = q_rot + (long)(b * NHH + h) * HDD;
  } else {
    int i = blk - BB * NHH;
    int b = i >> 3, kv = i & 7;
    src = xqkv + (long)b * QKVC + NHH * HDD + kv * HDD;
    dst = k_rot + (long)(b * NKVV + kv) * HDD;
  }
  vec[j] = src[j];
  __syncthreads();
  float a0 = 0.f, a1 = 0.f, a2 = 0.f, a3 = 0.f;
#pragma unroll
  for (int d0 = 0; d0 < HDD; d0 += 4) {
    a0 += vec[d0 + 0] * rot[(d0 + 0) * HDD + j];
    a1 += vec[d0 + 1] * rot[(d0 + 1) * HDD + j];
    a2 += vec[d0 + 2] * rot[(d0 + 2) * HDD + j];
    a3 += vec[d0 + 3] * rot[(d0 + 3) * HDD + j];
  }
  dst[j] = (a0 + a1) + (a2 + a3);
}

// ============ phase 1: QK^T raw scores (pure K stream) ======================
__global__ __launch_bounds__(256) void qk_scores(
    const float* __restrict__ q_rot, const float* __restrict__ k_rot,
    const float* __restrict__ cache_k, const int* __restrict__ curpos,
    float* __restrict__ scores) {
  __shared__ float sc[GG][CHUNK];  // 4KB
  const int blk = blockIdx.x;
  const int split = blk & (NSPLIT - 1);
  const int bkv = blk >> 4;
  const int b = bkv >> 3, kv = bkv & 7;
  const int cur = curpos[0];
  const int s0 = split * CHUNK;
  const int t = threadIdx.x, lane = t & 63, w = t >> 6;
  const int lg = lane & 15, grp = lane >> 4;

  float4 qa[GG], qb[GG];
#pragma unroll
  for (int g = 0; g < GG; ++g) {
    const float4* qp =
        (const float4*)(q_rot + (long)((b * NHH + kv * GG + g) * HDD));
    qa[g] = qp[lg];
    qb[g] = qp[lg + 16];
  }
  const float* kbase = cache_k + (long)(b * NKVV + kv) * SWW * HDD;
  const float* knew = k_rot + (long)(b * NKVV + kv) * HDD;

#pragma unroll 2
  for (int it = 0; it < 16; ++it) {
    const int sloc = w * 64 + it * 4 + grp;
    const int s = s0 + sloc;
    const float4* kp =
        (const float4*)((s == cur) ? knew : (kbase + (long)s * HDD));
    float4 ka = kp[lg];
    float4 kb = kp[lg + 16];
    float dots[GG];
#pragma unroll
    for (int g = 0; g < GG; ++g) {
      dots[g] = ka.x * qa[g].x + ka.y * qa[g].y + ka.z * qa[g].z +
                ka.w * qa[g].w + kb.x * qb[g].x + kb.y * qb[g].y +
                kb.z * qb[g].z + kb.w * qb[g].w;
    }
#pragma unroll
    for (int mm = 1; mm < 16; mm <<= 1) {
#pragma unroll
      for (int g = 0; g < GG; ++g) dots[g] += __shfl_xor(dots[g], mm);
    }
    if (lg == 0) {
#pragma unroll
      for (int g = 0; g < GG; ++g) sc[g][sloc] = dots[g];
    }
  }
  __syncthreads();
  for (int i = t; i < GG * CHUNK; i += 256) {
    int g = i >> 8, sl = i & (CHUNK - 1);
    scores[((long)(b * NHH + kv * GG + g)) * SWW + s0 + sl] = sc[g][sl];
  }
}

// ============ phase 2: exact row softmax (scale + mask) in place ============
__global__ __launch_bounds__(256) void softmax_row(
    float* __restrict__ scores, const float* __restrict__ mask) {
  __shared__ float red[4];
  const int bh = blockIdx.x;
  const int b = bh >> 5, h = bh & 31;
  const int t = threadIdx.x, lane = t & 63, w = t >> 6;
  float4* srow = (float4*)(scores + (long)bh * SWW);
  const float4* mrow = (const float4*)(mask + ((long)h * BB + b) * SWW);
  float4 e[4];
  float mx = -1e30f;
#pragma unroll
  for (int j = 0; j < 4; ++j) {
    float4 s4 = srow[t + j * 256];
    float4 m4 = mrow[t + j * 256];
    e[j].x = fmaf(s4.x, SCALE, m4.x);
    e[j].y = fmaf(s4.y, SCALE, m4.y);
    e[j].z = fmaf(s4.z, SCALE, m4.z);
    e[j].w = fmaf(s4.w, SCALE, m4.w);
    mx = fmaxf(mx, fmaxf(fmaxf(e[j].x, e[j].y), fmaxf(e[j].z, e[j].w)));
  }
#pragma unroll
  for (int mm = 1; mm < 64; mm <<= 1) mx = fmaxf(mx, __shfl_xor(mx, mm));
  if (lane == 0) red[w] = mx;
  __syncthreads();
  const float M = fmaxf(fmaxf(red[0], red[1]), fmaxf(red[2], red[3]));
  float sum = 0.f;
#pragma unroll
  for (int j = 0; j < 4; ++j) {
    e[j].x = __expf(e[j].x - M);
    e[j].y = __expf(e[j].y - M);
    e[j].z = __expf(e[j].z - M);
    e[j].w = __expf(e[j].w - M);
    sum += (e[j].x + e[j].y) + (e[j].z + e[j].w);
  }
#pragma unroll
  for (int mm = 1; mm < 64; mm <<= 1) sum += __shfl_xor(sum, mm);
  __syncthreads();
  if (lane == 0) red[w] = sum;
  __syncthreads();
  const float L = (red[0] + red[1]) + (red[2] + red[3]);
  const float rinv = 1.0f / L;
#pragma unroll
  for (int j = 0; j < 4; ++j) {
    e[j].x *= rinv;
    e[j].y *= rinv;
    e[j].z *= rinv;
    e[j].w *= rinv;
    srow[t + j * 256] = e[j];
  }
}

// ============ phase 3: PV partial (pure V stream, no shfl/exp in loop) ======
__global__ __launch_bounds__(256) void pv_partial(
    const float* __restrict__ probs, const float* __restrict__ xqkv,
    const float* __restrict__ cache_v, const int* __restrict__ curpos,
    float* __restrict__ pacc) {
  __shared__ float pr[GG][CHUNK];     // 4KB
  __shared__ float wacc[4][GG][HDD];  // 8KB
  const int blk = blockIdx.x;
  const int split = blk & (NSPLIT - 1);
  const int bkv = blk >> 4;
  const int b = bkv >> 3, kv = bkv & 7;
  const int cur = curpos[0];
  const int s0 = split * CHUNK;
  const int t = threadIdx.x, lane = t & 63, w = t >> 6;
  const int par = lane >> 5, dl = lane & 31;

  for (int i = t; i < GG * CHUNK; i += 256) {
    int g = i >> 8, sl = i & (CHUNK - 1);
    pr[g][sl] = probs[((long)(b * NHH + kv * GG + g)) * SWW + s0 + sl];
  }
  const float* vbase = cache_v + (long)(b * NKVV + kv) * SWW * HDD;
  const float* vnew =
      xqkv + (long)b * QKVC + NHH * HDD + NKVV * HDD + kv * HDD;
  __syncthreads();

  float4 a0 = make_float4(0, 0, 0, 0), a1 = a0, a2 = a0, a3 = a0;
#pragma unroll 4
  for (int it = 0; it < 32; ++it) {
    const int slp = w * 64 + it * 2 + par;
    const int s = s0 + slp;
    const float4* vp =
        (const float4*)((s == cur) ? vnew : (vbase + (long)s * HDD));
    float4 v4 = vp[dl];
    float p0 = pr[0][slp], p1 = pr[1][slp], p2 = pr[2][slp], p3 = pr[3][slp];
    a0.x = fmaf(p0, v4.x, a0.x);
    a0.y = fmaf(p0, v4.y, a0.y);
    a0.z = fmaf(p0, v4.z, a0.z);
    a0.w = fmaf(p0, v4.w, a0.w);
    a1.x = fmaf(p1, v4.x, a1.x);
    a1.y = fmaf(p1, v4.y, a1.y);
    a1.z = fmaf(p1, v4.z, a1.z);
    a1.w = fmaf(p1, v4.w, a1.w);
    a2.x = fmaf(p2, v4.x, a2.x);
    a2.y = fmaf(p2, v4.y, a2.y);
    a2.z = fmaf(p2, v4.z, a2.z);
    a2.w = fmaf(p2, v4.w, a2.w);
    a3.x = fmaf(p3, v4.x, a3.x);
    a3.y = fmaf(p3, v4.y, a3.y);
    a3.z = fmaf(p3, v4.z, a3.z);
    a3.w = fmaf(p3, v4.w, a3.w);
  }
  // reduce across the two key-parity halves of the wave
  a0.x += __shfl_xor(a0.x, 32);
  a0.y += __shfl_xor(a0.y, 32);
  a0.z += __shfl_xor(a0.z, 32);
  a0.w += __shfl_xor(a0.w, 32);
  a1.x += __shfl_xor(a1.x, 32);
  a1.y += __shfl_xor(a1.y, 32);
  a1.z += __shfl_xor(a1.z, 32);
  a1.w += __shfl_xor(a1.w, 32);
  a2.x += __shfl_xor(a2.x, 32);
  a2.y += __shfl_xor(a2.y, 32);
  a2.z += __shfl_xor(a2.z, 32);
  a2.w += __shfl_xor(a2.w, 32);
  a3.x += __shfl_xor(a3.x, 32);
  a3.y += __shfl_xor(a3.y, 32);
  a3.z += __shfl_xor(a3.z, 32);
  a3.w += __shfl_xor(a3.w, 32);
  if (par == 0) {
    *(float4*)&wacc[w][0][dl * 4] = a0;
    *(float4*)&wacc[w][1][dl * 4] = a1;
    *(float4*)&wacc[w][2][dl * 4] = a2;
    *(float4*)&wacc[w][3][dl * 4] = a3;
  }
  __syncthreads();
  for (int i = t; i < GG * HDD; i += 256) {
    int g = i >> 7, dd = i & (HDD - 1);
    float sv = (wacc[0][g][dd] + wacc[1][g][dd]) + (wacc[2][g][dd] + wacc[3][g][dd]);
    pacc[(((long)(b * NHH + kv * GG + g)) * NSPLIT + split) * HDD + dd] = sv;
  }
}

// ============ phase 4: plain-sum combine (probs pre-normalized) =============
__global__ __launch_bounds__(128) void sum_combine(
    const float* __restrict__ pacc, float* __restrict__ ctx) {
  const int bh = blockIdx.x;
  const int d = threadIdx.x;
  float a = 0.f;
#pragma unroll
  for (int i = 0; i < NSPLIT; ++i) a += pacc[((long)bh * NSPLIT + i) * HDD + d];
  ctx[(long)bh * HDD + d] = a;
}

extern "C" void kernel_launch(void* const* d_in, const int* in_sizes, int n_in,
                              void* d_out, int out_size, void* d_ws,
                              size_t ws_size, hipStream_t stream) {
  const float* x = (const float*)d_in[0];
  const float* wqkv = (const float*)d_in[1];
  const float* wo = (const float*)d_in[2];
  const float* rot = (const float*)d_in[3];
  const float* cache_k = (const float*)d_in[4];
  const float* cache_v = (const float*)d_in[5];
  const float* mask = (const float*)d_in[6];
  const int* curpos = (const int*)d_in[7];
  float* out = (float*)d_out;

  float* ws = (float*)d_ws;
  float* xqkv = ws;               // 196608
  float* q_rot = xqkv + 196608;   // 131072
  float* k_rot = q_rot + 131072;  // 32768
  float* ctx = k_rot + 32768;     // 131072
  float* pacc = ctx + 131072;     // 2097152
  float* big = pacc + 2097152;    // 4194304 (scores <-> gemm partials)
  (void)in_sizes; (void)n_in; (void)out_size; (void)ws_size;

  // QKV projection (split-K partials consumed before `big` becomes scores)
  hipLaunchKernelGGL(skinny_gemm_part, dim3(QKVC / 128, KSPB), dim3(256), 0,
                     stream, x, wqkv, big, DD, QKVC);
  hipLaunchKernelGGL(reduce_part, dim3((BB * QKVC) / 256), dim3(256), 0,
                     stream, big, xqkv, (long)BB * QKVC);
  hipLaunchKernelGGL(rotary_kernel, dim3(BB * NHH + BB * NKVV), dim3(128), 0,
                     stream, xqkv, rot, q_rot, k_rot);
  // attention: QK -> softmax -> PV -> combine
  hipLaunchKernelGGL(qk_scores, dim3(BB * NKVV * NSPLIT), dim3(256), 0, stream,
                     q_rot, k_rot, cache_k, curpos, big);
  hipLaunchKernelGGL(softmax_row, dim3(BB * NHH), dim3(256), 0, stream, big,
                     mask);
  hipLaunchKernelGGL(pv_partial, dim3(BB * NKVV * NSPLIT), dim3(256), 0,
                     stream, big, xqkv, cache_v, curpos, pacc);
  hipLaunchKernelGGL(sum_combine, dim3(BB * NHH), dim3(128), 0, stream, pacc,
                     ctx);
  // output projection (scores dead; `big` becomes WO partials)
  hipLaunchKernelGGL(skinny_gemm_part, dim3(DD / 128, KSPB), dim3(256), 0,
                     stream, ctx, wo, big, DD, DD);
  hipLaunchKernelGGL(reduce_part, dim3((BB * DD) / 256), dim3(256), 0, stream,
                     big, out, (long)BB * DD);
}

// Round 5
// 378.948 us; speedup vs baseline: 1.0488x; 1.0488x over previous
//
#include <hip/hip_runtime.h>

#define BB 32
#define NHH 32
#define NKVV 8
#define HDD 128
#define SWW 4096
#define DD 4096
#define GG 4
#define QKVC 6144
#define NSPLIT 16
#define CHUNK (SWW / NSPLIT)  // 256
#define KSPB 16

// ============ split-K skinny GEMM partial: part[ky][32][ncols] ==============
__global__ __launch_bounds__(256) void skinny_gemm_part(
    const float* __restrict__ x, const float* __restrict__ w,
    float* __restrict__ part, int K, int ncols) {
  __shared__ float2 red[4][64][8];
  const int t = threadIdx.x;
  const int ct = t & 63, kg = t >> 6;
  const long c0 = (long)blockIdx.x * 128 + ct * 2;
  const int Kb = K / KSPB;
  const int klen = Kb / 4;
  const int k0 = blockIdx.y * Kb + kg * klen;
  float2 acc[BB];
#pragma unroll
  for (int r = 0; r < BB; ++r) acc[r] = make_float2(0.f, 0.f);

#pragma unroll 2
  for (int k = k0; k < k0 + klen; k += 4) {
    float2 wv0 = *(const float2*)&w[(long)(k + 0) * ncols + c0];
    float2 wv1 = *(const float2*)&w[(long)(k + 1) * ncols + c0];
    float2 wv2 = *(const float2*)&w[(long)(k + 2) * ncols + c0];
    float2 wv3 = *(const float2*)&w[(long)(k + 3) * ncols + c0];
#pragma unroll
    for (int r = 0; r < BB; ++r) {
      float4 xv = *(const float4*)&x[r * K + k];
      acc[r].x = fmaf(xv.x, wv0.x, acc[r].x);
      acc[r].y = fmaf(xv.x, wv0.y, acc[r].y);
      acc[r].x = fmaf(xv.y, wv1.x, acc[r].x);
      acc[r].y = fmaf(xv.y, wv1.y, acc[r].y);
      acc[r].x = fmaf(xv.z, wv2.x, acc[r].x);
      acc[r].y = fmaf(xv.z, wv2.y, acc[r].y);
      acc[r].x = fmaf(xv.w, wv3.x, acc[r].x);
      acc[r].y = fmaf(xv.w, wv3.y, acc[r].y);
    }
  }
  for (int rc = 0; rc < 4; ++rc) {
    if (rc) __syncthreads();
#pragma unroll
    for (int j = 0; j < 8; ++j) red[kg][ct][j] = acc[rc * 8 + j];
    __syncthreads();
    if (kg == 0) {
#pragma unroll
      for (int j = 0; j < 8; ++j) {
        float2 s0 = red[0][ct][j], s1 = red[1][ct][j];
        float2 s2 = red[2][ct][j], s3 = red[3][ct][j];
        float2 sm = make_float2((s0.x + s1.x) + (s2.x + s3.x),
                                (s0.y + s1.y) + (s2.y + s3.y));
        *(float2*)&part[((long)blockIdx.y * BB + rc * 8 + j) * ncols + c0] = sm;
      }
    }
  }
}

// ============ reduce split-K partials =======================================
__global__ __launch_bounds__(256) void reduce_part(
    const float* __restrict__ part, float* __restrict__ out, long n) {
  long i = (long)blockIdx.x * 256 + threadIdx.x;
  if (i >= n) return;
  float s = 0.f;
#pragma unroll
  for (int j = 0; j < KSPB; ++j) s += part[(long)j * n + i];
  out[i] = s;
}

// ============ rotary ========================================================
__global__ __launch_bounds__(128) void rotary_kernel(
    const float* __restrict__ xqkv, const float* __restrict__ rot,
    float* __restrict__ q_rot, float* __restrict__ k_rot) {
  __shared__ float vec[HDD];
  const int blk = blockIdx.x;
  const int j = threadIdx.x;
  const float* src;
  float* dst;
  if (blk < BB * NHH) {
    int b = blk >> 5, h = blk & 31;
    src = xqkv + (long)b * QKVC + h * HDD;
    dst = q_rot + (long)(b * NHH + h) * HDD;
  } else {
    int i = blk - BB * NHH;
    int b = i >> 3, kv = i & 7;
    src = xqkv + (long)b * QKVC + NHH * HDD + kv * HDD;
    dst = k_rot + (long)(b * NKVV + kv) * HDD;
  }
  vec[j] = src[j];
  __syncthreads();
  float a0 = 0.f, a1 = 0.f, a2 = 0.f, a3 = 0.f;
#pragma unroll
  for (int d0 = 0; d0 < HDD; d0 += 4) {
    a0 += vec[d0 + 0] * rot[(d0 + 0) * HDD + j];
    a1 += vec[d0 + 1] * rot[(d0 + 1) * HDD + j];
    a2 += vec[d0 + 2] * rot[(d0 + 2) * HDD + j];
    a3 += vec[d0 + 3] * rot[(d0 + 3) * HDD + j];
  }
  dst[j] = (a0 + a1) + (a2 + a3);
}

// ============ flash-decode attention partial (one KV split) =================
// R2 structure + explicit prefetch pipelining in the two streaming loops.
__global__ __launch_bounds__(256) void attn_partial(
    const float* __restrict__ q_rot, const float* __restrict__ k_rot,
    const float* __restrict__ xqkv, const float* __restrict__ cache_k,
    const float* __restrict__ cache_v, const float* __restrict__ mask,
    const int* __restrict__ curpos, float* __restrict__ pm,
    float* __restrict__ pl, float* __restrict__ pacc) {
  __shared__ float4 scp[CHUNK];      // scores -> probs, [sl] x 4g
  __shared__ float4 mkp[CHUNK];      // mask preload
  __shared__ float red[4][GG][HDD];  // wave partials / reduce scratch

  const int blk = blockIdx.x;
  const int split = blk & (NSPLIT - 1);
  const int bkv = blk >> 4;
  const int b = bkv >> 3, kv = bkv & 7;
  const int cur = curpos[0];
  const int s0 = split * CHUNK;
  const int t = threadIdx.x, lane = t & 63, w = t >> 6;
  const int lg = lane & 15;
  const int grp = lane >> 4;
  const float scale = 0.08838834764831845f;  // 1/sqrt(128)

  // mask -> LDS (coalesced per g-row)
  for (int i = t; i < GG * CHUNK; i += 256) {
    int g = i >> 8;  // i / CHUNK
    int sl = i & (CHUNK - 1);
    ((float*)mkp)[sl * 4 + g] =
        mask[((long)(kv * GG + g) * BB + b) * SWW + s0 + sl];
  }

  // Q fragments: lane lg holds dims [lg*4..+3] and [64+lg*4..+3]
  float4 qa[GG], qb[GG];
#pragma unroll
  for (int g = 0; g < GG; ++g) {
    const float4* qp =
        (const float4*)(q_rot + (long)((b * NHH + kv * GG + g) * HDD));
    qa[g] = qp[lg];
    qb[g] = qp[lg + 16];
  }
  const float* kbase = cache_k + (long)(b * NKVV + kv) * SWW * HDD;
  const float* knew = k_rot + (long)(b * NKVV + kv) * HDD;
  __syncthreads();

  // ---- scores: wave handles 4 keys/iter, 16 lanes per key ----
  // depth-2 pipeline: next iter's K row is issued before this iter's chain.
  {
    auto krow = [&](int it) -> const float4* {
      const int s = s0 + w * 64 + it * 4 + grp;
      return (const float4*)((s == cur) ? knew : (kbase + (long)s * HDD));
    };
    const float4* kp0 = krow(0);
    float4 ka = kp0[lg];
    float4 kb = kp0[lg + 16];
#pragma unroll
    for (int it = 0; it < 16; ++it) {
      float4 kan, kbn;
      if (it < 15) {
        const float4* kpn = krow(it + 1);
        kan = kpn[lg];
        kbn = kpn[lg + 16];
      }
      float dots[GG];
#pragma unroll
      for (int g = 0; g < GG; ++g) {
        dots[g] = ka.x * qa[g].x + ka.y * qa[g].y + ka.z * qa[g].z +
                  ka.w * qa[g].w + kb.x * qb[g].x + kb.y * qb[g].y +
                  kb.z * qb[g].z + kb.w * qb[g].w;
      }
#pragma unroll
      for (int mm = 1; mm < 16; mm <<= 1) {
#pragma unroll
        for (int g = 0; g < GG; ++g) dots[g] += __shfl_xor(dots[g], mm);
      }
      if (lg == 0) {
        const int sloc = w * 64 + it * 4 + grp;
        float4 mv = mkp[sloc];
        float4 sv;
        sv.x = fmaf(dots[0], scale, mv.x);
        sv.y = fmaf(dots[1], scale, mv.y);
        sv.z = fmaf(dots[2], scale, mv.z);
        sv.w = fmaf(dots[3], scale, mv.w);
        scp[sloc] = sv;
      }
      ka = kan;
      kb = kbn;
    }
  }
  __syncthreads();

  // ---- softmax partial: thread owns one sl (float4 over g) ----
  const int sl = w * 64 + lane;
  float4 e = scp[sl];
  float4 mx = e;
#pragma unroll
  for (int m = 1; m < 64; m <<= 1) {
    mx.x = fmaxf(mx.x, __shfl_xor(mx.x, m));
    mx.y = fmaxf(mx.y, __shfl_xor(mx.y, m));
    mx.z = fmaxf(mx.z, __shfl_xor(mx.z, m));
    mx.w = fmaxf(mx.w, __shfl_xor(mx.w, m));
  }
  if (lane == 0) *(float4*)&red[w][0][0] = mx;
  __syncthreads();
  float4 m0 = *(const float4*)&red[0][0][0];
  float4 m1 = *(const float4*)&red[1][0][0];
  float4 m2 = *(const float4*)&red[2][0][0];
  float4 m3 = *(const float4*)&red[3][0][0];
  float4 Mx;
  Mx.x = fmaxf(fmaxf(m0.x, m1.x), fmaxf(m2.x, m3.x));
  Mx.y = fmaxf(fmaxf(m0.y, m1.y), fmaxf(m2.y, m3.y));
  Mx.z = fmaxf(fmaxf(m0.z, m1.z), fmaxf(m2.z, m3.z));
  Mx.w = fmaxf(fmaxf(m0.w, m1.w), fmaxf(m2.w, m3.w));
  float4 p;
  p.x = __expf(e.x - Mx.x);
  p.y = __expf(e.y - Mx.y);
  p.z = __expf(e.z - Mx.z);
  p.w = __expf(e.w - Mx.w);
  scp[sl] = p;
  float4 sm = p;
#pragma unroll
  for (int m = 1; m < 64; m <<= 1) {
    sm.x += __shfl_xor(sm.x, m);
    sm.y += __shfl_xor(sm.y, m);
    sm.z += __shfl_xor(sm.z, m);
    sm.w += __shfl_xor(sm.w, m);
  }
  if (lane == 0) *(float4*)&red[w][1][0] = sm;
  __syncthreads();
  float4 t0 = *(const float4*)&red[0][1][0];
  float4 t1 = *(const float4*)&red[1][1][0];
  float4 t2 = *(const float4*)&red[2][1][0];
  float4 t3 = *(const float4*)&red[3][1][0];
  if (t == 0) {
    long base = ((long)(b * NHH + kv * GG)) * NSPLIT + split;
    pm[base + 0 * NSPLIT] = Mx.x;
    pm[base + 1 * NSPLIT] = Mx.y;
    pm[base + 2 * NSPLIT] = Mx.z;
    pm[base + 3 * NSPLIT] = Mx.w;
    pl[base + 0 * NSPLIT] = (t0.x + t1.x) + (t2.x + t3.x);
    pl[base + 1 * NSPLIT] = (t0.y + t1.y) + (t2.y + t3.y);
    pl[base + 2 * NSPLIT] = (t0.z + t1.z) + (t2.z + t3.z);
    pl[base + 3 * NSPLIT] = (t0.w + t1.w) + (t2.w + t3.w);
  }
  __syncthreads();  // protect red reuse below

  // ---- PV: wave w covers its sl range; lane owns float4 of dims ----
  // depth-4 rotating prefetch: 4 independent V rows always in flight.
  const float* vbase = cache_v + (long)(b * NKVV + kv) * SWW * HDD;
  const float* vnew =
      xqkv + (long)b * QKVC + NHH * HDD + NKVV * HDD + kv * HDD;
  const int dl = lane & 31;
  const int half = lane >> 5;
  auto vrow = [&](int it) -> const float4* {
    const int s = s0 + w * 64 + it * 2 + half;
    return (const float4*)((s == cur) ? vnew : (vbase + (long)s * HDD)) + dl;
  };
  float4 acc0 = make_float4(0, 0, 0, 0), acc1 = acc0, acc2 = acc0,
         acc3 = acc0;
  float4 v0 = *vrow(0), v1 = *vrow(1), v2 = *vrow(2), v3 = *vrow(3);
#pragma unroll
  for (int it = 0; it < 32; it += 4) {
    float4 n0, n1, n2, n3;
    if (it + 4 < 32) {
      n0 = *vrow(it + 4);
      n1 = *vrow(it + 5);
      n2 = *vrow(it + 6);
      n3 = *vrow(it + 7);
    }
#pragma unroll
    for (int j = 0; j < 4; ++j) {
      const float4 vv = (j == 0) ? v0 : (j == 1) ? v1 : (j == 2) ? v2 : v3;
      const int slp = w * 64 + (it + j) * 2 + half;
      float4 p4 = scp[slp];
      acc0.x = fmaf(p4.x, vv.x, acc0.x);
      acc0.y = fmaf(p4.x, vv.y, acc0.y);
      acc0.z = fmaf(p4.x, vv.z, acc0.z);
      acc0.w = fmaf(p4.x, vv.w, acc0.w);
      acc1.x = fmaf(p4.y, vv.x, acc1.x);
      acc1.y = fmaf(p4.y, vv.y, acc1.y);
      acc1.z = fmaf(p4.y, vv.z, acc1.z);
      acc1.w = fmaf(p4.y, vv.w, acc1.w);
      acc2.x = fmaf(p4.z, vv.x, acc2.x);
      acc2.y = fmaf(p4.z, vv.y, acc2.y);
      acc2.z = fmaf(p4.z, vv.z, acc2.z);
      acc2.w = fmaf(p4.z, vv.w, acc2.w);
      acc3.x = fmaf(p4.w, vv.x, acc3.x);
      acc3.y = fmaf(p4.w, vv.y, acc3.y);
      acc3.z = fmaf(p4.w, vv.z, acc3.z);
      acc3.w = fmaf(p4.w, vv.w, acc3.w);
    }
    v0 = n0;
    v1 = n1;
    v2 = n2;
    v3 = n3;
  }
  // combine the two s-parity halves
  acc0.x += __shfl_xor(acc0.x, 32);
  acc0.y += __shfl_xor(acc0.y, 32);
  acc0.z += __shfl_xor(acc0.z, 32);
  acc0.w += __shfl_xor(acc0.w, 32);
  acc1.x += __shfl_xor(acc1.x, 32);
  acc1.y += __shfl_xor(acc1.y, 32);
  acc1.z += __shfl_xor(acc1.z, 32);
  acc1.w += __shfl_xor(acc1.w, 32);
  acc2.x += __shfl_xor(acc2.x, 32);
  acc2.y += __shfl_xor(acc2.y, 32);
  acc2.z += __shfl_xor(acc2.z, 32);
  acc2.w += __shfl_xor(acc2.w, 32);
  acc3.x += __shfl_xor(acc3.x, 32);
  acc3.y += __shfl_xor(acc3.y, 32);
  acc3.z += __shfl_xor(acc3.z, 32);
  acc3.w += __shfl_xor(acc3.w, 32);
  if (half == 0) {
    *(float4*)&red[w][0][dl * 4] = acc0;
    *(float4*)&red[w][1][dl * 4] = acc1;
    *(float4*)&red[w][2][dl * 4] = acc2;
    *(float4*)&red[w][3][dl * 4] = acc3;
  }
  __syncthreads();
  if (t < HDD) {
#pragma unroll
    for (int g = 0; g < GG; ++g) {
      float s = (red[0][g][t] + red[1][g][t]) + (red[2][g][t] + red[3][g][t]);
      pacc[(((long)(b * NHH + kv * GG + g)) * NSPLIT + split) * HDD + t] = s;
    }
  }
}

// ============ combine split partials -> ctx =================================
__global__ __launch_bounds__(128) void attn_combine(
    const float* __restrict__ pm, const float* __restrict__ pl,
    const float* __restrict__ pacc, float* __restrict__ ctx) {
  const int bh = blockIdx.x;
  const int d = threadIdx.x;
  float M = -1e30f;
#pragma unroll
  for (int i = 0; i < NSPLIT; ++i) M = fmaxf(M, pm[bh * NSPLIT + i]);
  float L = 0.f, a = 0.f;
#pragma unroll
  for (int i = 0; i < NSPLIT; ++i) {
    float wexp = __expf(pm[bh * NSPLIT + i] - M);
    L += pl[bh * NSPLIT + i] * wexp;
    a += wexp * pacc[((long)bh * NSPLIT + i) * HDD + d];
  }
  ctx[(long)bh * HDD + d] = a / L;
}

extern "C" void kernel_launch(void* const* d_in, const int* in_sizes, int n_in,
                              void* d_out, int out_size, void* d_ws,
                              size_t ws_size, hipStream_t stream) {
  const float* x = (const float*)d_in[0];
  const float* wqkv = (const float*)d_in[1];
  const float* wo = (const float*)d_in[2];
  const float* rot = (const float*)d_in[3];
  const float* cache_k = (const float*)d_in[4];
  const float* cache_v = (const float*)d_in[5];
  const float* mask = (const float*)d_in[6];
  const int* curpos = (const int*)d_in[7];
  float* out = (float*)d_out;

  float* ws = (float*)d_ws;
  float* xqkv = ws;               // 196608
  float* q_rot = xqkv + 196608;   // 131072
  float* k_rot = q_rot + 131072;  // 32768
  float* pm = k_rot + 32768;      // 16384
  float* pl = pm + 16384;         // 16384
  float* ctx = pl + 16384;        // 131072
  float* big = ctx + 131072;      // 3145728 (gemm partials / pacc, shared)
  (void)in_sizes; (void)n_in; (void)out_size; (void)ws_size;

  hipLaunchKernelGGL(skinny_gemm_part, dim3(QKVC / 128, KSPB), dim3(256), 0,
                     stream, x, wqkv, big, DD, QKVC);
  hipLaunchKernelGGL(reduce_part, dim3((BB * QKVC) / 256), dim3(256), 0,
                     stream, big, xqkv, (long)BB * QKVC);
  hipLaunchKernelGGL(rotary_kernel, dim3(BB * NHH + BB * NKVV), dim3(128), 0,
                     stream, xqkv, rot, q_rot, k_rot);
  hipLaunchKernelGGL(attn_partial, dim3(BB * NKVV * NSPLIT), dim3(256), 0,
                     stream, q_rot, k_rot, xqkv, cache_k, cache_v, mask,
                     curpos, pm, pl, big);
  hipLaunchKernelGGL(attn_combine, dim3(BB * NHH), dim3(128), 0, stream, pm,
                     pl, big, ctx);
  hipLaunchKernelGGL(skinny_gemm_part, dim3(DD / 128, KSPB), dim3(256), 0,
                     stream, ctx, wo, big, DD, DD);
  hipLaunchKernelGGL(reduce_part, dim3((BB * DD) / 256), dim3(256), 0, stream,
                     big, out, (long)BB * DD);
}